// Round 4
// baseline (210.624 us; speedup 1.0000x reference)
//
#include <hip/hip_runtime.h>

#define HID 4096
#define MD  128
#define SB  32768          // B*S rows total
#define SLEN 4096
#define NB  8
#define NH  10
#define WIN 10
#define TLEN (SLEN - WIN + 1)   // 4087
#define NEGV -1000000000.0f

typedef _Float16 f16x8 __attribute__((ext_vector_type(8)));
typedef float f32x4 __attribute__((ext_vector_type(4)));

__device__ __forceinline__ unsigned short f2h(float f) {
  _Float16 h = (_Float16)f;
  return __builtin_bit_cast(unsigned short, h);
}

__device__ __forceinline__ f16x8 cvt8(float4 u, float4 v) {
  f16x8 r;
  r[0] = (_Float16)u.x; r[1] = (_Float16)u.y; r[2] = (_Float16)u.z; r[3] = (_Float16)u.w;
  r[4] = (_Float16)v.x; r[5] = (_Float16)v.y; r[6] = (_Float16)v.z; r[7] = (_Float16)v.w;
  return r;
}

__device__ __forceinline__ void gl_lds16(const void* g, void* l) {
  __builtin_amdgcn_global_load_lds(
      (const __attribute__((address_space(1))) void*)g,
      (__attribute__((address_space(3))) void*)l, 16, 0, 0);
}

// ---------------- weight preconvert: fp32 -> fp16 planes in ws ----------------
__global__ void convert_k(const float* __restrict__ W1, const float* __restrict__ W2,
                          const float* __restrict__ Wq, const float* __restrict__ Wv,
                          unsigned short* __restrict__ w1h, unsigned short* __restrict__ w2h,
                          unsigned short* __restrict__ wqvh) {
  int i = blockIdx.x * 256 + threadIdx.x;
  if (i < MD * HID) w1h[i] = f2h(W1[i]);
  if (i < MD * MD)  w2h[i] = f2h(W2[i]);
  if (i < 32 * MD) {                       // 32 padded rows: 0-9 Wq, 10-19 Wv, 20-31 zero
    unsigned short v = 0;
    if (i < NH * MD)          v = f2h(Wq[i]);
    else if (i < 2 * NH * MD) v = f2h(Wv[i - NH * MD]);
    wqvh[i] = v;
  }
}

// ---------------- fused MLP + heads: counted-vmcnt pipeline ----------------
// grid 512 x 256 thr (4 waves). Block = 64 rows; wave w owns rows w*16..+16,
// ALL 128 output cols (no duplicate x loads). x -> registers directly in MFMA
// fragment layout; W1 via global_load_lds into a 3-deep 16KB ring. Loop never
// drains vmcnt to 0: asm s_waitcnt vmcnt(8) + raw s_barrier per step.
__global__ __launch_bounds__(256, 2) void fused_mlp(
    const float* __restrict__ x,
    const float* __restrict__ b1g, const float* __restrict__ b2g,
    const float* __restrict__ bvg,
    const unsigned short* __restrict__ w1h, const unsigned short* __restrict__ w2h,
    const unsigned short* __restrict__ wqvh,
    float* __restrict__ lv)
{
  __shared__ __align__(16) char smem[49152];   // 3 x 16KB ring; Y aliases [0,16KB)
  char* Y = smem;

  const int tid  = threadIdx.x;
  const int lane = tid & 63;
  const int w    = tid >> 6;
  const int l15  = lane & 15;
  const int j    = lane >> 4;
  const int m0   = blockIdx.x * 64;

  // B staging geometry: 16KB tile = [128 rows][128B], 4 chunks of 32 rows
  const int brow0 = tid >> 3;               // tid/8: rows 0..31 (chunk c adds 32)
  const int bkb   = (tid & 7) * 16;         // byte col within 128B row
  // x stream base: row = m0 + w*16 + l15, frag cols j*8 + {0..7} (+32)
  const float* xb = x + (size_t)(m0 + w * 16 + l15) * HID + j * 8;

  f32x4 acc[8] = {};
  float4 avA[4], avB[4];
  f16x8 af[2];

#define STAGEB(KT, BUFOFF)                                                     \
  {                                                                            \
    _Pragma("unroll")                                                          \
    for (int c = 0; c < 4; ++c) {                                              \
      int row = brow0 + c * 32;                                                \
      int kbs = bkb ^ ((row & 7) << 4);                                        \
      gl_lds16(w1h + (size_t)row * HID + (KT) * 64 + (kbs >> 1),               \
               smem + (BUFOFF) + c * 4096 + w * 1024);                         \
    }                                                                          \
  }

#define LOADX(AV, KT)                                                          \
  {                                                                            \
    const float* p = xb + (size_t)(KT) * 64;                                   \
    AV[0] = *(const float4*)(p);                                               \
    AV[1] = *(const float4*)(p + 4);                                           \
    AV[2] = *(const float4*)(p + 32);                                          \
    AV[3] = *(const float4*)(p + 36);                                          \
  }

#define CVT(AV) { af[0] = cvt8(AV[0], AV[1]); af[1] = cvt8(AV[2], AV[3]); }

#define DOMFMA(BUFOFF)                                                         \
  {                                                                            \
    _Pragma("unroll")                                                          \
    for (int ks = 0; ks < 2; ++ks) {                                           \
      f16x8 bf[8];                                                             \
      _Pragma("unroll")                                                        \
      for (int nf = 0; nf < 8; ++nf) {                                         \
        int n = nf * 16 + l15;                                                 \
        bf[nf] = *(const f16x8*)(smem + (BUFOFF) + n * 128 +                   \
                                 ((ks * 64 + j * 16) ^ ((n & 7) << 4)));       \
      }                                                                        \
      _Pragma("unroll")                                                        \
      for (int nf = 0; nf < 8; ++nf)                                           \
        acc[nf] = __builtin_amdgcn_mfma_f32_16x16x32_f16(af[ks], bf[nf],       \
                                                         acc[nf], 0, 0, 0);    \
    }                                                                          \
  }

#define WAITBAR()                                                              \
  asm volatile("s_waitcnt vmcnt(8)" ::: "memory");                             \
  __builtin_amdgcn_s_barrier();                                                \
  asm volatile("" ::: "memory");

  // prologue: B(0)->buf0, B(1)->buf1, x(0)->avA, x(1)->avB   [16 vm ops]
  STAGEB(0, 0);
  STAGEB(1, 16384);
  LOADX(avA, 0);
  LOADX(avB, 1);

  int bR = 0;   // ring offset holding B(kt)
  #pragma unroll 1
  for (int kt = 0; kt < 64; kt += 2) {
    // ---- step kt (x in avA, B in bR) ----
    WAITBAR();                                  // B(kt) guaranteed staged
    {
      int bW = bR + 32768; if (bW >= 49152) bW -= 49152;
      STAGEB((kt + 2) & 63, bW);                // +4 vm
    }
    CVT(avA);
    LOADX(avA, (kt + 2) & 63);                  // +4 vm
    DOMFMA(bR);
    bR += 16384; if (bR >= 49152) bR = 0;
    // ---- step kt+1 (x in avB, B in bR) ----
    WAITBAR();
    {
      int bW = bR + 32768; if (bW >= 49152) bW -= 49152;
      STAGEB((kt + 3) & 63, bW);
    }
    CVT(avB);
    LOADX(avB, (kt + 3) & 63);
    DOMFMA(bR);
    bR += 16384; if (bR >= 49152) bR = 0;
  }

  // full drain: stale ring stages must land before Y overwrites buf0
  asm volatile("s_waitcnt vmcnt(0)" ::: "memory");
  __builtin_amdgcn_s_barrier();
  asm volatile("" ::: "memory");

  // ---- y1 = relu(acc + b1) -> Y fp16 [64][256B] XOR-swizzled (per-wave rows) ----
  #pragma unroll
  for (int nf = 0; nf < 8; ++nf) {
    const int col = nf * 16 + l15;
    const float bb = b1g[col];
    #pragma unroll
    for (int r = 0; r < 4; ++r) {
      int row = w * 16 + j * 4 + r;
      float t = acc[nf][r] + bb; t = t > 0.f ? t : 0.f;
      *(unsigned short*)(Y + row * 256 + ((col * 2) ^ ((row & 7) << 4))) = f2h(t);
    }
  }

  // ---- layer 2: y2 = relu(y1 @ W2^T + b2), K=128; W2 frags from L2 ----
  f16x8 a2[4];
  {
    const int row = w * 16 + l15;
    const char* base = Y + row * 256;
    const int sw = (row & 7) << 4;
    #pragma unroll
    for (int ks = 0; ks < 4; ++ks)
      a2[ks] = *(const f16x8*)(base + ((ks * 64 + j * 16) ^ sw));
  }
  f32x4 acc2[8] = {};
  const unsigned short* w2b = w2h + (size_t)l15 * MD + j * 8;
  #pragma unroll
  for (int ks = 0; ks < 4; ++ks)
    #pragma unroll
    for (int nf = 0; nf < 8; ++nf) {
      f16x8 bf = *(const f16x8*)(w2b + (size_t)(nf * 16) * MD + ks * 32);
      acc2[nf] = __builtin_amdgcn_mfma_f32_16x16x32_f16(a2[ks], bf, acc2[nf], 0, 0, 0);
    }
  #pragma unroll
  for (int nf = 0; nf < 8; ++nf) {
    const int col = nf * 16 + l15;
    const float bb = b2g[col];
    #pragma unroll
    for (int r = 0; r < 4; ++r) {
      int row = w * 16 + j * 4 + r;
      float t = acc2[nf][r] + bb; t = t > 0.f ? t : 0.f;
      *(unsigned short*)(Y + row * 256 + ((col * 2) ^ ((row & 7) << 4))) = f2h(t);
    }
  }

  // ---- layer 3: heads (N=32 padded, 20 valid); Wqv frags from L2 ----
  f16x8 a3[4];
  {
    const int row = w * 16 + l15;
    const char* base = Y + row * 256;
    const int sw = (row & 7) << 4;
    #pragma unroll
    for (int ks = 0; ks < 4; ++ks)
      a3[ks] = *(const f16x8*)(base + ((ks * 64 + j * 16) ^ sw));
  }
  f32x4 acc3[2] = {};
  const unsigned short* wqb = wqvh + (size_t)l15 * MD + j * 8;
  #pragma unroll
  for (int ks = 0; ks < 4; ++ks)
    #pragma unroll
    for (int nt = 0; nt < 2; ++nt) {
      f16x8 bf = *(const f16x8*)(wqb + (size_t)(nt * 16) * MD + ks * 32);
      acc3[nt] = __builtin_amdgcn_mfma_f32_16x16x32_f16(a3[ks], bf, acc3[nt], 0, 0, 0);
    }
  #pragma unroll
  for (int nt = 0; nt < 2; ++nt) {
    const int col = nt * 16 + l15;
    if (col < 2 * NH) {
      const float badd = (col < NH) ? 0.f : bvg[col - NH];
      const size_t plane = (size_t)col * SB;
      #pragma unroll
      for (int r = 0; r < 4; ++r) {
        int s = m0 + w * 16 + j * 4 + r;
        lv[plane + s] = acc3[nt][r] + badd;
      }
    }
  }
}

// ---------------- sliding-window softmax + per-chunk max ----------------
__global__ void windows_k(const float* __restrict__ lv, const int* __restrict__ mask,
                          float* __restrict__ partial) {
  const int chunk = blockIdx.x, b = blockIdx.y, h = blockIdx.z;
  const int t0 = chunk * 256;
  const int tid = threadIdx.x;
  __shared__ float lsh[272], vsh[272];
  const float* lp = lv + (size_t)h * SB + b * SLEN;
  const float* vp = lv + (size_t)(NH + h) * SB + b * SLEN;
  const int* mp = mask + b * SLEN;
  for (int i = tid; i < 256 + WIN - 1; i += 256) {
    int t = t0 + i;
    if (t < SLEN) {
      float l = lp[t];
      if (mp[t] == 0) l = NEGV;
      lsh[i] = l; vsh[i] = vp[t];
    }
  }
  __syncthreads();
  float wmax = -INFINITY;
  int t = t0 + tid;
  if (t < TLEN) {
    float m = lsh[tid];
    #pragma unroll
    for (int jj = 1; jj < WIN; ++jj) m = fmaxf(m, lsh[tid + jj]);
    float den = 0.f, num = 0.f;
    #pragma unroll
    for (int jj = 0; jj < WIN; ++jj) {
      float e = __expf(lsh[tid + jj] - m);
      den += e; num += e * vsh[tid + jj];
    }
    wmax = num / den;
  }
  #pragma unroll
  for (int o = 32; o > 0; o >>= 1) wmax = fmaxf(wmax, __shfl_down(wmax, o, 64));
  __shared__ float red[4];
  if ((tid & 63) == 0) red[tid >> 6] = wmax;
  __syncthreads();
  if (tid == 0) {
    float r = fmaxf(fmaxf(red[0], red[1]), fmaxf(red[2], red[3]));
    partial[(b * NH + h) * 16 + chunk] = r;
  }
}

// ---------------- final: max over chunks, sum heads, + bias ----------------
__global__ void finalize_k(const float* __restrict__ partial, const float* __restrict__ bias,
                           float* __restrict__ out) {
  const int tid = threadIdx.x;  // 1 block, 128 thr
  __shared__ float hm[80];
  if (tid < NB * NH) {
    float m = -INFINITY;
    #pragma unroll
    for (int c = 0; c < 16; ++c) m = fmaxf(m, partial[tid * 16 + c]);
    hm[tid] = m;
  }
  __syncthreads();
  if (tid < NB) {
    float s = bias[0];
    #pragma unroll
    for (int h = 0; h < NH; ++h) s += hm[tid * NH + h];
    out[tid] = s;
  }
}

extern "C" void kernel_launch(void* const* d_in, const int* in_sizes, int n_in,
                              void* d_out, int out_size, void* d_ws, size_t ws_size,
                              hipStream_t stream) {
  const float* x    = (const float*)d_in[0];
  const int*   mask = (const int*)d_in[1];
  const float* W1   = (const float*)d_in[2];
  const float* b1   = (const float*)d_in[3];
  const float* W2   = (const float*)d_in[4];
  const float* b2   = (const float*)d_in[5];
  const float* Wq   = (const float*)d_in[6];
  const float* Wv   = (const float*)d_in[7];
  const float* bv   = (const float*)d_in[8];
  const float* bias = (const float*)d_in[9];

  char* ws = (char*)d_ws;
  unsigned short* w1h  = (unsigned short*)ws;                   // 1,048,576 B
  unsigned short* w2h  = (unsigned short*)(ws + 1048576);       //    32,768 B
  unsigned short* wqvh = (unsigned short*)(ws + 1081344);       //     8,192 B
  float* lv            = (float*)(ws + 1089536);                // 20*32768*4 = 2,621,440 B
  float* partial       = (float*)(ws + 3710976);                //     5,120 B
  float* out = (float*)d_out;

  hipLaunchKernelGGL(convert_k, dim3(2048), dim3(256), 0, stream, W1, W2, Wq, Wv, w1h, w2h, wqvh);
  hipLaunchKernelGGL(fused_mlp, dim3(SB / 64), dim3(256), 0, stream,
                     x, b1, b2, bv, w1h, w2h, wqvh, lv);
  hipLaunchKernelGGL(windows_k, dim3(16, NB, NH), dim3(256), 0, stream, lv, mask, partial);
  hipLaunchKernelGGL(finalize_k, dim3(1), dim3(128), 0, stream, partial, bias, out);
}

// Round 5
// 175.483 us; speedup vs baseline: 1.2003x; 1.2003x over previous
//
#include <hip/hip_runtime.h>

#define HID 4096
#define MD  128
#define SB  32768          // B*S rows total
#define SLEN 4096
#define NB  8
#define NH  10
#define WIN 10
#define TLEN (SLEN - WIN + 1)   // 4087
#define NEGV -1000000000.0f

typedef _Float16 f16x8 __attribute__((ext_vector_type(8)));
typedef float f32x4 __attribute__((ext_vector_type(4)));

__device__ __forceinline__ unsigned short f2h(float f) {
  _Float16 h = (_Float16)f;
  return __builtin_bit_cast(unsigned short, h);
}

__device__ __forceinline__ f16x8 cvt8(float4 u, float4 v) {
  f16x8 r;
  r[0] = (_Float16)u.x; r[1] = (_Float16)u.y; r[2] = (_Float16)u.z; r[3] = (_Float16)u.w;
  r[4] = (_Float16)v.x; r[5] = (_Float16)v.y; r[6] = (_Float16)v.z; r[7] = (_Float16)v.w;
  return r;
}

__device__ __forceinline__ void gl_lds16(const void* g, void* l) {
  __builtin_amdgcn_global_load_lds(
      (const __attribute__((address_space(1))) void*)g,
      (__attribute__((address_space(3))) void*)l, 16, 0, 0);
}

// ---------------- weight preconvert: fp32 -> fp16 planes in ws ----------------
__global__ void convert_k(const float* __restrict__ W1, const float* __restrict__ W2,
                          const float* __restrict__ Wq, const float* __restrict__ Wv,
                          unsigned short* __restrict__ w1h, unsigned short* __restrict__ w2h,
                          unsigned short* __restrict__ wqvh) {
  int i = blockIdx.x * 256 + threadIdx.x;
  if (i < MD * HID) w1h[i] = f2h(W1[i]);
  if (i < MD * MD)  w2h[i] = f2h(W2[i]);
  if (i < 32 * MD) {                       // 32 padded rows: 0-9 Wq, 10-19 Wv, 20-31 zero
    unsigned short v = 0;
    if (i < NH * MD)          v = f2h(Wq[i]);
    else if (i < 2 * NH * MD) v = f2h(Wv[i - NH * MD]);
    wqvh[i] = v;
  }
}

// ---------------- fused MLP + heads: 3-deep ring, counted vmcnt(4) ----------------
// grid 512 x 256 thr (4 waves). Block = 64 rows; wave w rows w*16..+16, all 128 cols.
// BK=32. Ring slot (16KB): A fp32 [64][128B] @0, B fp16 [128][64B] @8192. 3 slots=48KB.
// All staging via global_load_lds with coalesced pre-swizzled sources; one raw
// s_barrier + s_waitcnt vmcnt(4) per K-step (never drains). Y aliases slot0.
__global__ __launch_bounds__(256, 3) void fused_mlp(
    const float* __restrict__ x,
    const float* __restrict__ b1g, const float* __restrict__ b2g,
    const float* __restrict__ bvg,
    const unsigned short* __restrict__ w1h, const unsigned short* __restrict__ w2h,
    const unsigned short* __restrict__ wqvh,
    float* __restrict__ lv)
{
  __shared__ __align__(16) char smem[49152];
  char* Y = smem;

  const int tid  = threadIdx.x;
  const int lane = tid & 63;
  const int w    = tid >> 6;
  const int l15  = lane & 15;
  const int j    = lane >> 4;
  const int m0   = blockIdx.x * 64;

  // staging sources (pre-swizzled so LDS-linear dest == swizzled layout)
  const int aRow = tid >> 3;                                    // 0..31 (c1: +32)
  const int aCol = ((tid & 7) << 4) ^ ((aRow & 7) << 4);        // byte col in 128B row
  const int bRow = tid >> 2;                                    // 0..63 (c1: +64)
  const int bCol = ((tid & 3) << 4) ^ ((bRow & 3) << 4);        // byte col in 64B row
  const float* aS          = x   + (size_t)(m0 + aRow) * HID + (aCol >> 2);
  const unsigned short* bS = w1h + (size_t)bRow * HID + (bCol >> 1);

  f32x4 acc[8] = {};
  const int arow = w * 16 + l15;
  const int asw  = (arow & 7) << 4;

#define STAGE(APTR, BPTR, SLOTOFF)                                             \
  {                                                                            \
    gl_lds16((APTR),            smem + (SLOTOFF)         + w * 1024);          \
    gl_lds16((APTR) + 32 * HID, smem + (SLOTOFF) + 4096  + w * 1024);          \
    gl_lds16((BPTR),            smem + (SLOTOFF) + 8192  + w * 1024);          \
    gl_lds16((BPTR) + 64 * HID, smem + (SLOTOFF) + 12288 + w * 1024);          \
  }

#define DOMFMA(SLOTOFF)                                                        \
  {                                                                            \
    const char* Ab = smem + (SLOTOFF);                                         \
    const char* Bb = Ab + 8192;                                                \
    float4 a0 = *(const float4*)(Ab + arow * 128 + ((j * 32) ^ asw));          \
    float4 a1 = *(const float4*)(Ab + arow * 128 + ((j * 32 + 16) ^ asw));     \
    f16x8 af = cvt8(a0, a1);                                                   \
    f16x8 bf[8];                                                               \
    _Pragma("unroll")                                                          \
    for (int nf = 0; nf < 8; ++nf) {                                           \
      int n = nf * 16 + l15;                                                   \
      bf[nf] = *(const f16x8*)(Bb + n * 64 + ((j * 16) ^ ((n & 3) << 4)));     \
    }                                                                          \
    _Pragma("unroll")                                                          \
    for (int nf = 0; nf < 8; ++nf)                                             \
      acc[nf] = __builtin_amdgcn_mfma_f32_16x16x32_f16(af, bf[nf],             \
                                                       acc[nf], 0, 0, 0);      \
  }

#define WAITBAR(N)                                                             \
  asm volatile("s_waitcnt vmcnt(" #N ")" ::: "memory");                        \
  __builtin_amdgcn_s_barrier();                                                \
  asm volatile("" ::: "memory");

  // prologue: tiles 0,1 -> slots 0,1
  STAGE(aS, bS, 0);
  STAGE(aS + 32, bS + 32, 16384);

  int sR = 0, sW = 32768;
  const float* aP = aS + 64;
  const unsigned short* bP = bS + 64;

  #pragma unroll 1
  for (int t = 0; t < 126; ++t) {
    WAITBAR(4);                      // tile t landed; tile t+1 (4 ops) in flight
    STAGE(aP, bP, sW);               // tile t+2 -> slot (t+2)%3 (tile t-1's buffer)
    aP += 32; bP += 32;
    DOMFMA(sR);
    sR += 16384; if (sR == 49152) sR = 0;
    sW += 16384; if (sW == 49152) sW = 0;
  }
  // t = 126: no more staging
  WAITBAR(4);
  DOMFMA(sR);
  sR += 16384; if (sR == 49152) sR = 0;
  // t = 127: last tile, drain
  WAITBAR(0);
  DOMFMA(sR);
  __builtin_amdgcn_s_barrier();      // all reads of slot0 done before Y overwrites

  // ---- y1 = relu(acc + b1) -> Y fp16 [64][256B] XOR-swizzled (per-wave rows) ----
  #pragma unroll
  for (int nf = 0; nf < 8; ++nf) {
    const int col = nf * 16 + l15;
    const float bb = b1g[col];
    #pragma unroll
    for (int r = 0; r < 4; ++r) {
      int row = w * 16 + j * 4 + r;
      float t = acc[nf][r] + bb; t = t > 0.f ? t : 0.f;
      *(unsigned short*)(Y + row * 256 + ((col * 2) ^ ((row & 7) << 4))) = f2h(t);
    }
  }

  // ---- layer 2: y2 = relu(y1 @ W2^T + b2), K=128; W2 frags from L2 ----
  f16x8 a2[4];
  {
    const char* base = Y + arow * 256;
    #pragma unroll
    for (int ks = 0; ks < 4; ++ks)
      a2[ks] = *(const f16x8*)(base + ((ks * 64 + j * 16) ^ asw));
  }
  f32x4 acc2[8] = {};
  const unsigned short* w2b = w2h + (size_t)l15 * MD + j * 8;
  #pragma unroll
  for (int ks = 0; ks < 4; ++ks)
    #pragma unroll
    for (int nf = 0; nf < 8; ++nf) {
      f16x8 bf = *(const f16x8*)(w2b + (size_t)(nf * 16) * MD + ks * 32);
      acc2[nf] = __builtin_amdgcn_mfma_f32_16x16x32_f16(a2[ks], bf, acc2[nf], 0, 0, 0);
    }
  #pragma unroll
  for (int nf = 0; nf < 8; ++nf) {
    const int col = nf * 16 + l15;
    const float bb = b2g[col];
    #pragma unroll
    for (int r = 0; r < 4; ++r) {
      int row = w * 16 + j * 4 + r;
      float t = acc2[nf][r] + bb; t = t > 0.f ? t : 0.f;
      *(unsigned short*)(Y + row * 256 + ((col * 2) ^ ((row & 7) << 4))) = f2h(t);
    }
  }

  // ---- layer 3: heads (N=32 padded, 20 valid); Wqv frags from L2 ----
  f16x8 a3[4];
  {
    const char* base = Y + arow * 256;
    #pragma unroll
    for (int ks = 0; ks < 4; ++ks)
      a3[ks] = *(const f16x8*)(base + ((ks * 64 + j * 16) ^ asw));
  }
  f32x4 acc3[2] = {};
  const unsigned short* wqb = wqvh + (size_t)l15 * MD + j * 8;
  #pragma unroll
  for (int ks = 0; ks < 4; ++ks)
    #pragma unroll
    for (int nt = 0; nt < 2; ++nt) {
      f16x8 bf = *(const f16x8*)(wqb + (size_t)(nt * 16) * MD + ks * 32);
      acc3[nt] = __builtin_amdgcn_mfma_f32_16x16x32_f16(a3[ks], bf, acc3[nt], 0, 0, 0);
    }
  #pragma unroll
  for (int nt = 0; nt < 2; ++nt) {
    const int col = nt * 16 + l15;
    if (col < 2 * NH) {
      const float badd = (col < NH) ? 0.f : bvg[col - NH];
      const size_t plane = (size_t)col * SB;
      #pragma unroll
      for (int r = 0; r < 4; ++r) {
        int s = m0 + w * 16 + j * 4 + r;
        lv[plane + s] = acc3[nt][r] + badd;
      }
    }
  }
}

// ---------------- sliding-window softmax + per-chunk max ----------------
__global__ void windows_k(const float* __restrict__ lv, const int* __restrict__ mask,
                          float* __restrict__ partial) {
  const int chunk = blockIdx.x, b = blockIdx.y, h = blockIdx.z;
  const int t0 = chunk * 256;
  const int tid = threadIdx.x;
  __shared__ float lsh[272], vsh[272];
  const float* lp = lv + (size_t)h * SB + b * SLEN;
  const float* vp = lv + (size_t)(NH + h) * SB + b * SLEN;
  const int* mp = mask + b * SLEN;
  for (int i = tid; i < 256 + WIN - 1; i += 256) {
    int t = t0 + i;
    if (t < SLEN) {
      float l = lp[t];
      if (mp[t] == 0) l = NEGV;
      lsh[i] = l; vsh[i] = vp[t];
    }
  }
  __syncthreads();
  float wmax = -INFINITY;
  int t = t0 + tid;
  if (t < TLEN) {
    float m = lsh[tid];
    #pragma unroll
    for (int jj = 1; jj < WIN; ++jj) m = fmaxf(m, lsh[tid + jj]);
    float den = 0.f, num = 0.f;
    #pragma unroll
    for (int jj = 0; jj < WIN; ++jj) {
      float e = __expf(lsh[tid + jj] - m);
      den += e; num += e * vsh[tid + jj];
    }
    wmax = num / den;
  }
  #pragma unroll
  for (int o = 32; o > 0; o >>= 1) wmax = fmaxf(wmax, __shfl_down(wmax, o, 64));
  __shared__ float red[4];
  if ((tid & 63) == 0) red[tid >> 6] = wmax;
  __syncthreads();
  if (tid == 0) {
    float r = fmaxf(fmaxf(red[0], red[1]), fmaxf(red[2], red[3]));
    partial[(b * NH + h) * 16 + chunk] = r;
  }
}

// ---------------- final: max over chunks, sum heads, + bias ----------------
__global__ void finalize_k(const float* __restrict__ partial, const float* __restrict__ bias,
                           float* __restrict__ out) {
  const int tid = threadIdx.x;  // 1 block, 128 thr
  __shared__ float hm[80];
  if (tid < NB * NH) {
    float m = -INFINITY;
    #pragma unroll
    for (int c = 0; c < 16; ++c) m = fmaxf(m, partial[tid * 16 + c]);
    hm[tid] = m;
  }
  __syncthreads();
  if (tid < NB) {
    float s = bias[0];
    #pragma unroll
    for (int h = 0; h < NH; ++h) s += hm[tid * NH + h];
    out[tid] = s;
  }
}

extern "C" void kernel_launch(void* const* d_in, const int* in_sizes, int n_in,
                              void* d_out, int out_size, void* d_ws, size_t ws_size,
                              hipStream_t stream) {
  const float* x    = (const float*)d_in[0];
  const int*   mask = (const int*)d_in[1];
  const float* W1   = (const float*)d_in[2];
  const float* b1   = (const float*)d_in[3];
  const float* W2   = (const float*)d_in[4];
  const float* b2   = (const float*)d_in[5];
  const float* Wq   = (const float*)d_in[6];
  const float* Wv   = (const float*)d_in[7];
  const float* bv   = (const float*)d_in[8];
  const float* bias = (const float*)d_in[9];

  char* ws = (char*)d_ws;
  unsigned short* w1h  = (unsigned short*)ws;                   // 1,048,576 B
  unsigned short* w2h  = (unsigned short*)(ws + 1048576);       //    32,768 B
  unsigned short* wqvh = (unsigned short*)(ws + 1081344);       //     8,192 B
  float* lv            = (float*)(ws + 1089536);                // 20*32768*4 = 2,621,440 B
  float* partial       = (float*)(ws + 3710976);                //     5,120 B
  float* out = (float*)d_out;

  hipLaunchKernelGGL(convert_k, dim3(2048), dim3(256), 0, stream, W1, W2, Wq, Wv, w1h, w2h, wqvh);
  hipLaunchKernelGGL(fused_mlp, dim3(SB / 64), dim3(256), 0, stream,
                     x, b1, b2, bv, w1h, w2h, wqvh, lv);
  hipLaunchKernelGGL(windows_k, dim3(16, NB, NH), dim3(256), 0, stream, lv, mask, partial);
  hipLaunchKernelGGL(finalize_k, dim3(1), dim3(128), 0, stream, partial, bias, out);
}

// Round 6
// 164.302 us; speedup vs baseline: 1.2819x; 1.0680x over previous
//
#include <hip/hip_runtime.h>

#define HID 4096
#define MD  128
#define SB  32768          // B*S rows total
#define SLEN 4096
#define NB  8
#define NH  10
#define WIN 10
#define TLEN (SLEN - WIN + 1)   // 4087
#define NEGV -1000000000.0f
#define SLOT 24576
#define LDSZ 73728

typedef _Float16 f16x8 __attribute__((ext_vector_type(8)));
typedef float f32x4 __attribute__((ext_vector_type(4)));

__device__ __forceinline__ unsigned short f2h(float f) {
  _Float16 h = (_Float16)f;
  return __builtin_bit_cast(unsigned short, h);
}

__device__ __forceinline__ void gl_lds16(const void* g, void* l) {
  __builtin_amdgcn_global_load_lds(
      (const __attribute__((address_space(1))) void*)g,
      (__attribute__((address_space(3))) void*)l, 16, 0, 0);
}

// ---------------- weight preconvert: fp32 -> fp16 planes in ws ----------------
__global__ void convert_k(const float* __restrict__ W1, const float* __restrict__ W2,
                          const float* __restrict__ Wq, const float* __restrict__ Wv,
                          unsigned short* __restrict__ w1h, unsigned short* __restrict__ w2h,
                          unsigned short* __restrict__ wqvh) {
  int i = blockIdx.x * 256 + threadIdx.x;
  if (i < MD * HID) w1h[i] = f2h(W1[i]);
  if (i < MD * MD)  w2h[i] = f2h(W2[i]);
  if (i < 32 * MD) {                       // 32 padded rows: 0-9 Wq, 10-19 Wv, 20-31 zero
    unsigned short v = 0;
    if (i < NH * MD)          v = f2h(Wq[i]);
    else if (i < 2 * NH * MD) v = f2h(Wv[i - NH * MD]);
    wqvh[i] = v;
  }
}

// ---------------- fused MLP + heads: 3-slot ring, BK=64, counted vmcnt ----------------
// grid 512 x 256 thr. Block = 64 rows. 2x2 wave grid: wave (wr,wc) = rows wr*32+..,
// cols wc*64+.. Slot (24KB) = A fp16 [64][128B] + B fp16 [128][128B], XOR-swizzled.
// A: reg-staged (coalesced float4 x4) -> cvt fp16 -> ds_write one iter later.
// B: global_load_lds, pre-swizzled source. One barrier + one vmcnt(8) per 64-K step.
__global__ __launch_bounds__(256, 2) void fused_mlp(
    const float* __restrict__ x,
    const float* __restrict__ b1g, const float* __restrict__ b2g,
    const float* __restrict__ bvg,
    const unsigned short* __restrict__ w1h, const unsigned short* __restrict__ w2h,
    const unsigned short* __restrict__ wqvh,
    float* __restrict__ lv)
{
  __shared__ __align__(16) char smem[LDSZ];
  char* Y = smem;   // epilogue reuse of slot0 (16KB)

  const int tid  = threadIdx.x;
  const int lane = tid & 63;
  const int w    = tid >> 6;
  const int wr   = w >> 1, wc = w & 1;
  const int l15  = lane & 15;
  const int j    = lane >> 4;
  const int m0   = blockIdx.x * 64;

  // A source: row (tid>>4)+p*16, float col (tid&15)*4  (coalesced 256B/row/instr)
  const float* xA = x + (size_t)(m0 + (tid >> 4)) * HID + (tid & 15) * 4;
  // B staging: chunk c rows c*32+(tid>>3), 16B col (tid&7)*16, source pre-swizzled
  const int bRow = tid >> 3;
  const int bSc  = ((tid & 7) << 4) ^ ((bRow & 7) << 4);
  const unsigned short* bS0 = w1h + (size_t)bRow * HID + (bSc >> 1);

  f32x4 acc[2][4] = {};
  float4 avA[4], avB[4];

#define LOADA(AV, KT)                                                          \
  {                                                                            \
    const float* p_ = xA + (size_t)(KT) * 64;                                  \
    AV[0] = *(const float4*)(p_);                                              \
    AV[1] = *(const float4*)(p_ + 16 * HID);                                   \
    AV[2] = *(const float4*)(p_ + 32 * HID);                                   \
    AV[3] = *(const float4*)(p_ + 48 * HID);                                   \
  }

#define STAGEB(KT, SOFF)                                                       \
  {                                                                            \
    gl_lds16(bS0 + (size_t)(KT) * 64,            smem + (SOFF) + 8192  + w * 1024); \
    gl_lds16(bS0 + (size_t)(KT) * 64 + 32 * HID, smem + (SOFF) + 12288 + w * 1024); \
    gl_lds16(bS0 + (size_t)(KT) * 64 + 64 * HID, smem + (SOFF) + 16384 + w * 1024); \
    gl_lds16(bS0 + (size_t)(KT) * 64 + 96 * HID, smem + (SOFF) + 20480 + w * 1024); \
  }

#define WRITEA(AV, SOFF)                                                       \
  {                                                                            \
    _Pragma("unroll")                                                          \
    for (int p = 0; p < 4; ++p) {                                              \
      int row = p * 16 + (tid >> 4);                                           \
      ushort4 o;                                                               \
      o.x = f2h(AV[p].x); o.y = f2h(AV[p].y);                                  \
      o.z = f2h(AV[p].z); o.w = f2h(AV[p].w);                                  \
      *(ushort4*)(smem + (SOFF) + row * 128 +                                  \
                  (((tid & 15) * 8) ^ ((row & 7) << 4))) = o;                  \
    }                                                                          \
  }

#define DOMFMA(SOFF)                                                           \
  {                                                                            \
    const char* Ab = smem + (SOFF);                                            \
    const char* Bb = Ab + 8192;                                                \
    _Pragma("unroll")                                                          \
    for (int ks = 0; ks < 2; ++ks) {                                           \
      f16x8 af[2];                                                             \
      _Pragma("unroll")                                                        \
      for (int mf = 0; mf < 2; ++mf) {                                         \
        int rr = wr * 32 + mf * 16 + l15;                                      \
        af[mf] = *(const f16x8*)(Ab + rr * 128 +                               \
                                 ((ks * 64 + j * 16) ^ ((rr & 7) << 4)));      \
      }                                                                        \
      _Pragma("unroll")                                                        \
      for (int nf = 0; nf < 4; ++nf) {                                         \
        int n = wc * 64 + nf * 16 + l15;                                       \
        f16x8 bf = *(const f16x8*)(Bb + n * 128 +                              \
                                   ((ks * 64 + j * 16) ^ ((n & 7) << 4)));     \
        acc[0][nf] = __builtin_amdgcn_mfma_f32_16x16x32_f16(af[0], bf,         \
                                                            acc[0][nf], 0, 0, 0); \
        acc[1][nf] = __builtin_amdgcn_mfma_f32_16x16x32_f16(af[1], bf,         \
                                                            acc[1][nf], 0, 0, 0); \
      }                                                                        \
    }                                                                          \
  }

#define TOPBAR()                                                               \
  asm volatile("s_waitcnt lgkmcnt(0)" ::: "memory");                           \
  __builtin_amdgcn_s_barrier();                                                \
  asm volatile("" ::: "memory");

#define MIDW8() asm volatile("s_waitcnt vmcnt(8)" ::: "memory");

  // prologue: tiles 0,1
  LOADA(avA, 0); STAGEB(0, 0);
  LOADA(avB, 1); STAGEB(1, SLOT);
  asm volatile("s_waitcnt vmcnt(12)" ::: "memory");   // A(0) regs landed
  WRITEA(avA, 0);

  int sR = 0, sW = 2 * SLOT;
  #pragma unroll 1
  for (int t = 0; t < 62; t += 2) {
    int sN;
    // even iter t: avB holds A(t+1)
    TOPBAR();                                   // slot(t) fully valid
    LOADA(avA, t + 2); STAGEB(t + 2, sW);       // 8 vm ops
    MIDW8();                                    // A(t+1),B(t+1) landed
    sN = sR + SLOT; if (sN == LDSZ) sN = 0;
    WRITEA(avB, sN);                            // A(t+1) -> slot(t+1)
    DOMFMA(sR);
    sR = sN; sW += SLOT; if (sW == LDSZ) sW = 0;
    // odd iter t+1: avA holds A(t+2)
    TOPBAR();
    LOADA(avB, t + 3); STAGEB(t + 3, sW);
    MIDW8();
    sN = sR + SLOT; if (sN == LDSZ) sN = 0;
    WRITEA(avA, sN);
    DOMFMA(sR);
    sR = sN; sW += SLOT; if (sW == LDSZ) sW = 0;
  }
  // t = 62: avB holds A(63); outstanding = A(63),B(63)
  TOPBAR();
  asm volatile("s_waitcnt vmcnt(4)" ::: "memory");    // A(63) regs landed
  {
    int sN = sR + SLOT; if (sN == LDSZ) sN = 0;
    WRITEA(avB, sN);                                  // -> slot0
    DOMFMA(sR);
    sR = sN;
  }
  // t = 63
  asm volatile("s_waitcnt lgkmcnt(0) vmcnt(0)" ::: "memory");  // A(63) write + B(63) landed
  __builtin_amdgcn_s_barrier();
  asm volatile("" ::: "memory");
  DOMFMA(sR);                                         // slot0
  __syncthreads();                                    // all slot0 reads done before Y overwrite

  // ---- y1 = relu(acc + b1) -> Y fp16 [64][256B] XOR-swizzled ----
  #pragma unroll
  for (int nf = 0; nf < 4; ++nf) {
    const int col = wc * 64 + nf * 16 + l15;
    const float bb = b1g[col];
    #pragma unroll
    for (int mf = 0; mf < 2; ++mf)
      #pragma unroll
      for (int r = 0; r < 4; ++r) {
        float t = acc[mf][nf][r] + bb; t = t > 0.f ? t : 0.f;
        int row = wr * 32 + mf * 16 + j * 4 + r;
        *(unsigned short*)(Y + row * 256 + ((col * 2) ^ ((row & 7) << 4))) = f2h(t);
      }
  }
  __syncthreads();

  // ---- layer 2: y2 = relu(y1 @ W2^T + b2), K=128; wave-private rows w*16.. ----
  const int erow = w * 16 + l15;
  const int esw  = (erow & 7) << 4;
  f16x8 a2[4];
  {
    const char* base = Y + erow * 256;
    #pragma unroll
    for (int ks = 0; ks < 4; ++ks)
      a2[ks] = *(const f16x8*)(base + ((ks * 64 + j * 16) ^ esw));
  }
  f32x4 acc2[8] = {};
  const unsigned short* w2b = w2h + (size_t)l15 * MD + j * 8;
  #pragma unroll
  for (int ks = 0; ks < 4; ++ks)
    #pragma unroll
    for (int nf = 0; nf < 8; ++nf) {
      f16x8 bf = *(const f16x8*)(w2b + (size_t)(nf * 16) * MD + ks * 32);
      acc2[nf] = __builtin_amdgcn_mfma_f32_16x16x32_f16(a2[ks], bf, acc2[nf], 0, 0, 0);
    }
  #pragma unroll
  for (int nf = 0; nf < 8; ++nf) {
    const int col = nf * 16 + l15;
    const float bb = b2g[col];
    #pragma unroll
    for (int r = 0; r < 4; ++r) {
      int row = w * 16 + j * 4 + r;
      float t = acc2[nf][r] + bb; t = t > 0.f ? t : 0.f;
      *(unsigned short*)(Y + row * 256 + ((col * 2) ^ ((row & 7) << 4))) = f2h(t);
    }
  }

  // ---- layer 3: heads (N=32 padded, 20 valid); wave-private rows ----
  f16x8 a3[4];
  {
    const char* base = Y + erow * 256;
    #pragma unroll
    for (int ks = 0; ks < 4; ++ks)
      a3[ks] = *(const f16x8*)(base + ((ks * 64 + j * 16) ^ esw));
  }
  f32x4 acc3[2] = {};
  const unsigned short* wqb = wqvh + (size_t)l15 * MD + j * 8;
  #pragma unroll
  for (int ks = 0; ks < 4; ++ks)
    #pragma unroll
    for (int nt = 0; nt < 2; ++nt) {
      f16x8 bf = *(const f16x8*)(wqb + (size_t)(nt * 16) * MD + ks * 32);
      acc3[nt] = __builtin_amdgcn_mfma_f32_16x16x32_f16(a3[ks], bf, acc3[nt], 0, 0, 0);
    }
  #pragma unroll
  for (int nt = 0; nt < 2; ++nt) {
    const int col = nt * 16 + l15;
    if (col < 2 * NH) {
      const float badd = (col < NH) ? 0.f : bvg[col - NH];
      const size_t plane = (size_t)col * SB;
      #pragma unroll
      for (int r = 0; r < 4; ++r) {
        int s = m0 + w * 16 + j * 4 + r;
        lv[plane + s] = acc3[nt][r] + badd;
      }
    }
  }
}

// ---------------- sliding-window softmax + per-chunk max ----------------
__global__ void windows_k(const float* __restrict__ lv, const int* __restrict__ mask,
                          float* __restrict__ partial) {
  const int chunk = blockIdx.x, b = blockIdx.y, h = blockIdx.z;
  const int t0 = chunk * 256;
  const int tid = threadIdx.x;
  __shared__ float lsh[272], vsh[272];
  const float* lp = lv + (size_t)h * SB + b * SLEN;
  const float* vp = lv + (size_t)(NH + h) * SB + b * SLEN;
  const int* mp = mask + b * SLEN;
  for (int i = tid; i < 256 + WIN - 1; i += 256) {
    int t = t0 + i;
    if (t < SLEN) {
      float l = lp[t];
      if (mp[t] == 0) l = NEGV;
      lsh[i] = l; vsh[i] = vp[t];
    }
  }
  __syncthreads();
  float wmax = -INFINITY;
  int t = t0 + tid;
  if (t < TLEN) {
    float m = lsh[tid];
    #pragma unroll
    for (int jj = 1; jj < WIN; ++jj) m = fmaxf(m, lsh[tid + jj]);
    float den = 0.f, num = 0.f;
    #pragma unroll
    for (int jj = 0; jj < WIN; ++jj) {
      float e = __expf(lsh[tid + jj] - m);
      den += e; num += e * vsh[tid + jj];
    }
    wmax = num / den;
  }
  #pragma unroll
  for (int o = 32; o > 0; o >>= 1) wmax = fmaxf(wmax, __shfl_down(wmax, o, 64));
  __shared__ float red[4];
  if ((tid & 63) == 0) red[tid >> 6] = wmax;
  __syncthreads();
  if (tid == 0) {
    float r = fmaxf(fmaxf(red[0], red[1]), fmaxf(red[2], red[3]));
    partial[(b * NH + h) * 16 + chunk] = r;
  }
}

// ---------------- final: max over chunks, sum heads, + bias ----------------
__global__ void finalize_k(const float* __restrict__ partial, const float* __restrict__ bias,
                           float* __restrict__ out) {
  const int tid = threadIdx.x;  // 1 block, 128 thr
  __shared__ float hm[80];
  if (tid < NB * NH) {
    float m = -INFINITY;
    #pragma unroll
    for (int c = 0; c < 16; ++c) m = fmaxf(m, partial[tid * 16 + c]);
    hm[tid] = m;
  }
  __syncthreads();
  if (tid < NB) {
    float s = bias[0];
    #pragma unroll
    for (int h = 0; h < NH; ++h) s += hm[tid * NH + h];
    out[tid] = s;
  }
}

extern "C" void kernel_launch(void* const* d_in, const int* in_sizes, int n_in,
                              void* d_out, int out_size, void* d_ws, size_t ws_size,
                              hipStream_t stream) {
  const float* x    = (const float*)d_in[0];
  const int*   mask = (const int*)d_in[1];
  const float* W1   = (const float*)d_in[2];
  const float* b1   = (const float*)d_in[3];
  const float* W2   = (const float*)d_in[4];
  const float* b2   = (const float*)d_in[5];
  const float* Wq   = (const float*)d_in[6];
  const float* Wv   = (const float*)d_in[7];
  const float* bv   = (const float*)d_in[8];
  const float* bias = (const float*)d_in[9];

  char* ws = (char*)d_ws;
  unsigned short* w1h  = (unsigned short*)ws;                   // 1,048,576 B
  unsigned short* w2h  = (unsigned short*)(ws + 1048576);       //    32,768 B
  unsigned short* wqvh = (unsigned short*)(ws + 1081344);       //     8,192 B
  float* lv            = (float*)(ws + 1089536);                // 20*32768*4 = 2,621,440 B
  float* partial       = (float*)(ws + 3710976);                //     5,120 B
  float* out = (float*)d_out;

  hipLaunchKernelGGL(convert_k, dim3(2048), dim3(256), 0, stream, W1, W2, Wq, Wv, w1h, w2h, wqvh);
  hipLaunchKernelGGL(fused_mlp, dim3(SB / 64), dim3(256), 0, stream,
                     x, b1, b2, bv, w1h, w2h, wqvh, lv);
  hipLaunchKernelGGL(windows_k, dim3(16, NB, NH), dim3(256), 0, stream, lv, mask, partial);
  hipLaunchKernelGGL(finalize_k, dim3(1), dim3(128), 0, stream, partial, bias, out);
}

// Round 8
// 152.008 us; speedup vs baseline: 1.3856x; 1.0809x over previous
//
#include <hip/hip_runtime.h>

#define HID 4096
#define MD  128
#define SB  32768          // B*S rows total
#define SLEN 4096
#define NB  8
#define NH  10
#define WIN 10
#define TLEN (SLEN - WIN + 1)   // 4087
#define NEGV -1000000000.0f
#define SLOT 49152
#define LDSZ 147456        // 3 slots

typedef _Float16 f16x8 __attribute__((ext_vector_type(8)));
typedef float f32x4 __attribute__((ext_vector_type(4)));
typedef const __attribute__((address_space(1))) f32x4* gf4p;

__device__ __forceinline__ unsigned short f2h(float f) {
  _Float16 h = (_Float16)f;
  return __builtin_bit_cast(unsigned short, h);
}

__device__ __forceinline__ f16x8 cvt8(f32x4 u, f32x4 v) {
  f16x8 r;
  r[0] = (_Float16)u[0]; r[1] = (_Float16)u[1]; r[2] = (_Float16)u[2]; r[3] = (_Float16)u[3];
  r[4] = (_Float16)v[0]; r[5] = (_Float16)v[1]; r[6] = (_Float16)v[2]; r[7] = (_Float16)v[3];
  return r;
}

__device__ __forceinline__ void gl_lds16(const void* g, void* l) {
  __builtin_amdgcn_global_load_lds(
      (const __attribute__((address_space(1))) void*)g,
      (__attribute__((address_space(3))) void*)l, 16, 0, 0);
}

// ---------------- weight preconvert: fp32 -> fp16 planes in ws ----------------
__global__ void convert_k(const float* __restrict__ W1, const float* __restrict__ W2,
                          const float* __restrict__ Wq, const float* __restrict__ Wv,
                          unsigned short* __restrict__ w1h, unsigned short* __restrict__ w2h,
                          unsigned short* __restrict__ wqvh) {
  int i = blockIdx.x * 256 + threadIdx.x;
  if (i < MD * HID) w1h[i] = f2h(W1[i]);
  if (i < MD * MD)  w2h[i] = f2h(W2[i]);
  if (i < 32 * MD) {                       // 32 padded rows: 0-9 Wq, 10-19 Wv, 20-31 zero
    unsigned short v = 0;
    if (i < NH * MD)          v = f2h(Wq[i]);
    else if (i < 2 * NH * MD) v = f2h(Wv[i - NH * MD]);
    wqvh[i] = v;
  }
}

// ---------------- fused MLP + heads: BK=128, 512 thr, ring-3, counted vmcnt ----------------
// grid 512 x 512 thr (8 waves), 1 block/CU (147KB LDS) -> 16384 resident x-streams,
// 512B chunks. Wave (wr,wc) = rows wr*32+.., cols wc*32+.. Slot: A fp16 [64][256B] @0,
// B fp16 [128][256B] @16384. A reg-staged+cvt (write one step later), B via gl_lds.
// One lgkmcnt(0)+barrier per step; vmcnt(8) mid-step -- VMEM queue never drains.
__global__ __launch_bounds__(512, 2) void fused_mlp(
    const float* __restrict__ x,
    const float* __restrict__ b1g, const float* __restrict__ b2g,
    const float* __restrict__ bvg,
    const unsigned short* __restrict__ w1h, const unsigned short* __restrict__ w2h,
    const unsigned short* __restrict__ wqvh,
    float* __restrict__ lv)
{
  extern __shared__ __align__(16) char smem[];
  char* Y = smem;   // epilogue reuse of slot0

  const int tid  = threadIdx.x;
  const int lane = tid & 63;
  const int w    = tid >> 6;           // 0..7
  const int wr   = w >> 2, wc = w & 3;
  const int l15  = lane & 15;
  const int j    = lane >> 4;
  const int m0   = blockIdx.x * 64;

  // A: thread covers row tid>>3 (0..63), floats (tid&7)*16 .. +16 (64B contiguous)
  const int aRow = tid >> 3;
  const int aSw  = (aRow & 7) << 4;
  const int aC0  = ((tid & 7) * 32) ^ aSw;
  const float* xA = x + (size_t)(m0 + aRow) * HID + (tid & 7) * 16;

  f32x4 acc[2][2] = {};
  f32x4 avA[4], avB[4];

#define LOADA(AV, KT)                                                          \
  {                                                                            \
    const float* p_ = xA + (size_t)(KT) * 128;                                 \
    AV[0] = *(gf4p)(p_);                                                       \
    AV[1] = *(gf4p)(p_ + 4);                                                   \
    AV[2] = *(gf4p)(p_ + 8);                                                   \
    AV[3] = *(gf4p)(p_ + 12);                                                  \
  }

#define STAGEB(KT, SOFF)                                                       \
  {                                                                            \
    _Pragma("unroll")                                                          \
    for (int c = 0; c < 4; ++c) {                                              \
      int row = w * 16 + c * 4 + j;                                            \
      int cb  = (l15 << 4) ^ ((row & 7) << 4);                                 \
      gl_lds16(w1h + (size_t)row * HID + (KT) * 128 + (cb >> 1),               \
               smem + (SOFF) + 16384 + (w * 4 + c) * 1024);                    \
    }                                                                          \
  }

#define WRITEA(AV, SOFF)                                                       \
  {                                                                            \
    f16x8 h0_ = cvt8(AV[0], AV[1]);                                            \
    f16x8 h1_ = cvt8(AV[2], AV[3]);                                            \
    char* d_ = smem + (SOFF) + aRow * 256;                                     \
    *(f16x8*)(d_ + aC0) = h0_;                                                 \
    *(f16x8*)(d_ + (aC0 ^ 16)) = h1_;                                          \
  }

#define DOMFMA(SOFF)                                                           \
  {                                                                            \
    const char* Ab = smem + (SOFF);                                            \
    const char* Bb = Ab + 16384;                                               \
    _Pragma("unroll")                                                          \
    for (int ks = 0; ks < 4; ++ks) {                                           \
      f16x8 af[2], bf[2];                                                      \
      _Pragma("unroll")                                                        \
      for (int mf = 0; mf < 2; ++mf) {                                         \
        int rr = wr * 32 + mf * 16 + l15;                                      \
        af[mf] = *(const f16x8*)(Ab + rr * 256 +                               \
                                 ((ks * 64 + j * 16) ^ ((rr & 7) << 4)));      \
      }                                                                        \
      _Pragma("unroll")                                                        \
      for (int nf = 0; nf < 2; ++nf) {                                         \
        int n = wc * 32 + nf * 16 + l15;                                       \
        bf[nf] = *(const f16x8*)(Bb + n * 256 +                                \
                                 ((ks * 64 + j * 16) ^ ((n & 7) << 4)));       \
      }                                                                        \
      _Pragma("unroll")                                                        \
      for (int mf = 0; mf < 2; ++mf)                                           \
        _Pragma("unroll")                                                      \
        for (int nf = 0; nf < 2; ++nf)                                         \
          acc[mf][nf] = __builtin_amdgcn_mfma_f32_16x16x32_f16(af[mf], bf[nf], \
                                                          acc[mf][nf], 0, 0, 0); \
    }                                                                          \
  }

#define TOPBAR()                                                               \
  asm volatile("s_waitcnt lgkmcnt(0)" ::: "memory");                           \
  __builtin_amdgcn_s_barrier();                                                \
  asm volatile("" ::: "memory");

#define MIDW8() asm volatile("s_waitcnt vmcnt(8)" ::: "memory");

  // prologue: tiles 0,1 (16 vm ops)
  LOADA(avA, 0); STAGEB(0, 0);
  LOADA(avB, 1); STAGEB(1, SLOT);
  asm volatile("s_waitcnt vmcnt(12)" ::: "memory");   // A(0) landed
  WRITEA(avA, 0);

  int sR = 0, sW = 2 * SLOT;
  #pragma unroll 1
  for (int t = 0; t < 30; t += 2) {
    int sN;
    // even t: avB holds A(t+1)
    TOPBAR();                                   // slot(t) valid (A via lgkm, B via last MIDW8)
    LOADA(avA, t + 2); STAGEB(t + 2, sW);       // 8 vm ops -> slot(t+2)
    MIDW8();                                    // A(t+1)+B(t+1) landed; t+2's 8 in flight
    sN = sR + SLOT; if (sN == LDSZ) sN = 0;
    WRITEA(avB, sN);                            // A(t+1) -> slot(t+1)
    DOMFMA(sR);
    sR = sN; sW += SLOT; if (sW == LDSZ) sW = 0;
    // odd t+1: avA holds A(t+2)
    TOPBAR();
    LOADA(avB, t + 3); STAGEB(t + 3, sW);
    MIDW8();
    sN = sR + SLOT; if (sN == LDSZ) sN = 0;
    WRITEA(avA, sN);
    DOMFMA(sR);
    sR = sN; sW += SLOT; if (sW == LDSZ) sW = 0;
  }
  // t = 30: outstanding = A(31),B(31)
  TOPBAR();
  asm volatile("s_waitcnt vmcnt(4)" ::: "memory");    // A(31) landed
  {
    int sN = sR + SLOT; if (sN == LDSZ) sN = 0;
    WRITEA(avB, sN);
    DOMFMA(sR);
    sR = sN;
  }
  // t = 31
  asm volatile("s_waitcnt lgkmcnt(0) vmcnt(0)" ::: "memory");
  __builtin_amdgcn_s_barrier();
  asm volatile("" ::: "memory");
  DOMFMA(sR);

  // ---- y1 = relu(acc + b1) -> Y fp16 [64][256B] (slot0; last read fenced at t=31 barrier) ----
  #pragma unroll
  for (int mf = 0; mf < 2; ++mf)
    #pragma unroll
    for (int nf = 0; nf < 2; ++nf) {
      const int col = wc * 32 + nf * 16 + l15;
      const float bb = b1g[col];
      #pragma unroll
      for (int r = 0; r < 4; ++r) {
        float t = acc[mf][nf][r] + bb; t = t > 0.f ? t : 0.f;
        int row = wr * 32 + mf * 16 + j * 4 + r;
        *(unsigned short*)(Y + row * 256 + ((col * 2) ^ ((row & 7) << 4))) = f2h(t);
      }
    }
  __syncthreads();

  // ---- layer 2: y2 = relu(y1 @ W2^T + b2), K=128 ----
  // wave w: row-group g = w>>1 (16 rows), col-half ch = w&1 (64 cols)
  const int g  = w >> 1, ch = w & 1;
  const int erow = g * 16 + l15;
  const int esw  = (erow & 7) << 4;
  f16x8 a2[4];
  {
    const char* base = Y + erow * 256;
    #pragma unroll
    for (int ks = 0; ks < 4; ++ks)
      a2[ks] = *(const f16x8*)(base + ((ks * 64 + j * 16) ^ esw));
  }
  f32x4 acc2[4] = {};
  const unsigned short* w2b = w2h + (size_t)(ch * 64 + l15) * MD + j * 8;
  #pragma unroll
  for (int ks = 0; ks < 4; ++ks)
    #pragma unroll
    for (int nf = 0; nf < 4; ++nf) {
      f16x8 bf = *(const f16x8*)(w2b + (size_t)(nf * 16) * MD + ks * 32);
      acc2[nf] = __builtin_amdgcn_mfma_f32_16x16x32_f16(a2[ks], bf, acc2[nf], 0, 0, 0);
    }
  __syncthreads();   // all Y reads done before overwrite
  #pragma unroll
  for (int nf = 0; nf < 4; ++nf) {
    const int col = ch * 64 + nf * 16 + l15;
    const float bb = b2g[col];
    #pragma unroll
    for (int r = 0; r < 4; ++r) {
      int row = g * 16 + j * 4 + r;
      float t = acc2[nf][r] + bb; t = t > 0.f ? t : 0.f;
      *(unsigned short*)(Y + row * 256 + ((col * 2) ^ ((row & 7) << 4))) = f2h(t);
    }
  }
  __syncthreads();

  // ---- layer 3: heads (N=32 padded, 20 valid). wave w: rows g*16.., cols (w&1)*16.. ----
  f16x8 a3[4];
  {
    const char* base = Y + erow * 256;
    #pragma unroll
    for (int ks = 0; ks < 4; ++ks)
      a3[ks] = *(const f16x8*)(base + ((ks * 64 + j * 16) ^ esw));
  }
  f32x4 acc3 = {};
  const int col3 = ch * 16 + l15;
  const unsigned short* wqb = wqvh + (size_t)col3 * MD + j * 8;
  #pragma unroll
  for (int ks = 0; ks < 4; ++ks) {
    f16x8 bf = *(const f16x8*)(wqb + ks * 32);
    acc3 = __builtin_amdgcn_mfma_f32_16x16x32_f16(a3[ks], bf, acc3, 0, 0, 0);
  }
  if (col3 < 2 * NH) {
    const float badd = (col3 < NH) ? 0.f : bvg[col3 - NH];
    const size_t plane = (size_t)col3 * SB;
    #pragma unroll
    for (int r = 0; r < 4; ++r) {
      int s = m0 + g * 16 + j * 4 + r;
      lv[plane + s] = acc3[r] + badd;
    }
  }
}

// ---------------- sliding-window softmax + per-chunk max ----------------
__global__ void windows_k(const float* __restrict__ lv, const int* __restrict__ mask,
                          float* __restrict__ partial) {
  const int chunk = blockIdx.x, b = blockIdx.y, h = blockIdx.z;
  const int t0 = chunk * 256;
  const int tid = threadIdx.x;
  __shared__ float lsh[272], vsh[272];
  const float* lp = lv + (size_t)h * SB + b * SLEN;
  const float* vp = lv + (size_t)(NH + h) * SB + b * SLEN;
  const int* mp = mask + b * SLEN;
  for (int i = tid; i < 256 + WIN - 1; i += 256) {
    int t = t0 + i;
    if (t < SLEN) {
      float l = lp[t];
      if (mp[t] == 0) l = NEGV;
      lsh[i] = l; vsh[i] = vp[t];
    }
  }
  __syncthreads();
  float wmax = -INFINITY;
  int t = t0 + tid;
  if (t < TLEN) {
    float m = lsh[tid];
    #pragma unroll
    for (int jj = 1; jj < WIN; ++jj) m = fmaxf(m, lsh[tid + jj]);
    float den = 0.f, num = 0.f;
    #pragma unroll
    for (int jj = 0; jj < WIN; ++jj) {
      float e = __expf(lsh[tid + jj] - m);
      den += e; num += e * vsh[tid + jj];
    }
    wmax = num / den;
  }
  #pragma unroll
  for (int o = 32; o > 0; o >>= 1) wmax = fmaxf(wmax, __shfl_down(wmax, o, 64));
  __shared__ float red[4];
  if ((tid & 63) == 0) red[tid >> 6] = wmax;
  __syncthreads();
  if (tid == 0) {
    float r = fmaxf(fmaxf(red[0], red[1]), fmaxf(red[2], red[3]));
    partial[(b * NH + h) * 16 + chunk] = r;
  }
}

// ---------------- final: max over chunks, sum heads, + bias ----------------
__global__ void finalize_k(const float* __restrict__ partial, const float* __restrict__ bias,
                           float* __restrict__ out) {
  const int tid = threadIdx.x;  // 1 block, 128 thr
  __shared__ float hm[80];
  if (tid < NB * NH) {
    float m = -INFINITY;
    #pragma unroll
    for (int c = 0; c < 16; ++c) m = fmaxf(m, partial[tid * 16 + c]);
    hm[tid] = m;
  }
  __syncthreads();
  if (tid < NB) {
    float s = bias[0];
    #pragma unroll
    for (int h = 0; h < NH; ++h) s += hm[tid * NH + h];
    out[tid] = s;
  }
}

extern "C" void kernel_launch(void* const* d_in, const int* in_sizes, int n_in,
                              void* d_out, int out_size, void* d_ws, size_t ws_size,
                              hipStream_t stream) {
  const float* x    = (const float*)d_in[0];
  const int*   mask = (const int*)d_in[1];
  const float* W1   = (const float*)d_in[2];
  const float* b1   = (const float*)d_in[3];
  const float* W2   = (const float*)d_in[4];
  const float* b2   = (const float*)d_in[5];
  const float* Wq   = (const float*)d_in[6];
  const float* Wv   = (const float*)d_in[7];
  const float* bv   = (const float*)d_in[8];
  const float* bias = (const float*)d_in[9];

  char* ws = (char*)d_ws;
  unsigned short* w1h  = (unsigned short*)ws;                   // 1,048,576 B
  unsigned short* w2h  = (unsigned short*)(ws + 1048576);       //    32,768 B
  unsigned short* wqvh = (unsigned short*)(ws + 1081344);       //     8,192 B
  float* lv            = (float*)(ws + 1089536);                // 20*32768*4 = 2,621,440 B
  float* partial       = (float*)(ws + 3710976);                //     5,120 B
  float* out = (float*)d_out;

  hipLaunchKernelGGL(convert_k, dim3(2048), dim3(256), 0, stream, W1, W2, Wq, Wv, w1h, w2h, wqvh);
  hipLaunchKernelGGL(fused_mlp, dim3(SB / 64), dim3(512), LDSZ, stream,
                     x, b1, b2, bv, w1h, w2h, wqvh, lv);
  hipLaunchKernelGGL(windows_k, dim3(16, NB, NH), dim3(256), 0, stream, lv, mask, partial);
  hipLaunchKernelGGL(finalize_k, dim3(1), dim3(128), 0, stream, partial, bias, out);
}

// Round 9
// 135.739 us; speedup vs baseline: 1.5517x; 1.1199x over previous
//
#include <hip/hip_runtime.h>

#define HID 4096
#define MD  128
#define SB  32768          // B*S rows total
#define SLEN 4096
#define NB  8
#define NH  10
#define WIN 10
#define TLEN (SLEN - WIN + 1)   // 4087
#define NEGV -1000000000.0f
#define SLOT 49152
#define LDSZ 147456        // 3 slots

typedef _Float16 f16x8 __attribute__((ext_vector_type(8)));
typedef float f32x4 __attribute__((ext_vector_type(4)));
typedef const __attribute__((address_space(1))) f32x4* gf4p;

__device__ __forceinline__ unsigned short f2h(float f) {
  _Float16 h = (_Float16)f;
  return __builtin_bit_cast(unsigned short, h);
}

__device__ __forceinline__ f16x8 cvt8(f32x4 u, f32x4 v) {
  f16x8 r;
  r[0] = (_Float16)u[0]; r[1] = (_Float16)u[1]; r[2] = (_Float16)u[2]; r[3] = (_Float16)u[3];
  r[4] = (_Float16)v[0]; r[5] = (_Float16)v[1]; r[6] = (_Float16)v[2]; r[7] = (_Float16)v[3];
  return r;
}

__device__ __forceinline__ void gl_lds16(const void* g, void* l) {
  __builtin_amdgcn_global_load_lds(
      (const __attribute__((address_space(1))) void*)g,
      (__attribute__((address_space(3))) void*)l, 16, 0, 0);
}

// ---------------- weight preconvert: fp32 -> fp16 planes in ws ----------------
__global__ void convert_k(const float* __restrict__ W1, const float* __restrict__ W2,
                          const float* __restrict__ Wq, const float* __restrict__ Wv,
                          unsigned short* __restrict__ w1h, unsigned short* __restrict__ w2h,
                          unsigned short* __restrict__ wqvh) {
  int i = blockIdx.x * 256 + threadIdx.x;
  if (i < MD * HID) w1h[i] = f2h(W1[i]);
  if (i < MD * MD)  w2h[i] = f2h(W2[i]);
  if (i < 32 * MD) {                       // 32 padded rows: 0-9 Wq, 10-19 Wv, 20-31 zero
    unsigned short v = 0;
    if (i < NH * MD)          v = f2h(Wq[i]);
    else if (i < 2 * NH * MD) v = f2h(Wv[i - NH * MD]);
    wqvh[i] = v;
  }
}

// ---------------- fused MLP + heads: BK=128, depth-3 A-prefetch in regs ----------------
// grid 512 x 512 thr (8 waves), 1 block/CU. Slot (48KB): A fp16 [64][256B] @0,
// B fp16 [128][256B] @16384; ring-3. At step t: issue A(t+3)->regs + B(t+2)->LDS,
// ds_write A(t+1), compute tile t. Steady in-flight: 16 VMEM ops/thread (8KB/wave
// of HBM A-reads). One vmcnt(8)+lgkmcnt(0)+barrier per step; queue never drains.
__global__ __launch_bounds__(512, 2) void fused_mlp(
    const float* __restrict__ x,
    const float* __restrict__ b1g, const float* __restrict__ b2g,
    const float* __restrict__ bvg,
    const unsigned short* __restrict__ w1h, const unsigned short* __restrict__ w2h,
    const unsigned short* __restrict__ wqvh,
    float* __restrict__ lv)
{
  extern __shared__ __align__(16) char smem[];
  char* Y = smem;   // epilogue reuse of slot0 A-region (tile31 lives in slot1)

  const int tid  = threadIdx.x;
  const int lane = tid & 63;
  const int w    = tid >> 6;           // 0..7
  const int wr   = w >> 2, wc = w & 3;
  const int l15  = lane & 15;
  const int j    = lane >> 4;
  const int m0   = blockIdx.x * 64;

  // A: thread covers row tid>>3 (0..63), 64B contiguous at byte col (tid&7)*64
  const int aRow = tid >> 3;
  const int aSw  = (aRow & 7) << 4;
  const int aC0  = ((tid & 7) * 32) ^ aSw;
  const float* xA = x + (size_t)(m0 + aRow) * HID + (tid & 7) * 16;

  f32x4 acc[2][2] = {};
  f32x4 av0[4], av1[4], av2[4];

#define LOADA(AV, KT)                                                          \
  {                                                                            \
    const float* p_ = xA + (size_t)(KT) * 128;                                 \
    AV[0] = *(gf4p)(p_);                                                       \
    AV[1] = *(gf4p)(p_ + 4);                                                   \
    AV[2] = *(gf4p)(p_ + 8);                                                   \
    AV[3] = *(gf4p)(p_ + 12);                                                  \
  }

#define STAGEB(KT, SOFF)                                                       \
  {                                                                            \
    _Pragma("unroll")                                                          \
    for (int c = 0; c < 4; ++c) {                                              \
      int row = w * 16 + c * 4 + j;                                            \
      int cb  = (l15 << 4) ^ ((row & 7) << 4);                                 \
      gl_lds16(w1h + (size_t)row * HID + (KT) * 128 + (cb >> 1),               \
               smem + (SOFF) + 16384 + (w * 4 + c) * 1024);                    \
    }                                                                          \
  }

#define WRITEA(AV, SOFF)                                                       \
  {                                                                            \
    f16x8 h0_ = cvt8(AV[0], AV[1]);                                            \
    f16x8 h1_ = cvt8(AV[2], AV[3]);                                            \
    char* d_ = smem + (SOFF) + aRow * 256;                                     \
    *(f16x8*)(d_ + aC0) = h0_;                                                 \
    *(f16x8*)(d_ + (aC0 ^ 16)) = h1_;                                          \
  }

#define DOMFMA(SOFF)                                                           \
  {                                                                            \
    const char* Ab = smem + (SOFF);                                            \
    const char* Bb = Ab + 16384;                                               \
    _Pragma("unroll")                                                          \
    for (int ks = 0; ks < 4; ++ks) {                                           \
      f16x8 af[2], bf[2];                                                      \
      _Pragma("unroll")                                                        \
      for (int mf = 0; mf < 2; ++mf) {                                         \
        int rr = wr * 32 + mf * 16 + l15;                                      \
        af[mf] = *(const f16x8*)(Ab + rr * 256 +                               \
                                 ((ks * 64 + j * 16) ^ ((rr & 7) << 4)));      \
      }                                                                        \
      _Pragma("unroll")                                                        \
      for (int nf = 0; nf < 2; ++nf) {                                         \
        int n = wc * 32 + nf * 16 + l15;                                       \
        bf[nf] = *(const f16x8*)(Bb + n * 256 +                                \
                                 ((ks * 64 + j * 16) ^ ((n & 7) << 4)));       \
      }                                                                        \
      _Pragma("unroll")                                                        \
      for (int mf = 0; mf < 2; ++mf)                                           \
        _Pragma("unroll")                                                      \
        for (int nf = 0; nf < 2; ++nf)                                         \
          acc[mf][nf] = __builtin_amdgcn_mfma_f32_16x16x32_f16(af[mf], bf[nf], \
                                                          acc[mf][nf], 0, 0, 0); \
    }                                                                          \
  }

#define TOPBAR()                                                               \
  asm volatile("s_waitcnt vmcnt(8) lgkmcnt(0)" ::: "memory");                  \
  __builtin_amdgcn_s_barrier();                                                \
  asm volatile("" ::: "memory");

#define BODY(T, AVW, AVL)                                                      \
  TOPBAR();                                                                    \
  LOADA(AVL, (T) + 3);                                                         \
  STAGEB((T) + 2, sW);                                                         \
  { int sN_ = sR + SLOT; if (sN_ == LDSZ) sN_ = 0; WRITEA(AVW, sN_); }         \
  DOMFMA(sR);                                                                  \
  sR += SLOT; if (sR == LDSZ) sR = 0;                                          \
  sW += SLOT; if (sW == LDSZ) sW = 0;

  // prologue: A0,B0,A1,B1,A2 issued (20 ops); A0 landed after vmcnt(16)
  LOADA(av0, 0); STAGEB(0, 0);
  LOADA(av1, 1); STAGEB(1, SLOT);
  LOADA(av2, 2);
  asm volatile("s_waitcnt vmcnt(16)" ::: "memory");
  WRITEA(av0, 0);

  int sR = 0, sW = 2 * SLOT;
  // steady: t = 0..26 (all guards true: A up to 29, B up to 28)
  #pragma unroll 1
  for (int tb = 0; tb < 27; tb += 3) {
    BODY(tb + 0, av1, av0);
    BODY(tb + 1, av2, av1);
    BODY(tb + 2, av0, av2);
  }
  // t=27: A30, B29
  TOPBAR(); LOADA(av0, 30); STAGEB(29, sW);
  { int sN_ = sR + SLOT; if (sN_ == LDSZ) sN_ = 0; WRITEA(av1, sN_); }
  DOMFMA(sR);
  sR += SLOT; if (sR == LDSZ) sR = 0; sW += SLOT; if (sW == LDSZ) sW = 0;
  // t=28: A31, B30
  TOPBAR(); LOADA(av1, 31); STAGEB(30, sW);
  { int sN_ = sR + SLOT; if (sN_ == LDSZ) sN_ = 0; WRITEA(av2, sN_); }
  DOMFMA(sR);
  sR += SLOT; if (sR == LDSZ) sR = 0; sW += SLOT; if (sW == LDSZ) sW = 0;
  // t=29: B31
  TOPBAR(); STAGEB(31, sW);
  { int sN_ = sR + SLOT; if (sN_ == LDSZ) sN_ = 0; WRITEA(av0, sN_); }
  DOMFMA(sR);
  sR += SLOT; if (sR == LDSZ) sR = 0;
  // t=30: drain all VMEM (A31 + B31)
  asm volatile("s_waitcnt vmcnt(0) lgkmcnt(0)" ::: "memory");
  __builtin_amdgcn_s_barrier();
  asm volatile("" ::: "memory");
  { int sN_ = sR + SLOT; if (sN_ == LDSZ) sN_ = 0; WRITEA(av1, sN_); }
  DOMFMA(sR);
  sR += SLOT; if (sR == LDSZ) sR = 0;
  // t=31 (slot1; Y=slot0 A-region is disjoint)
  asm volatile("s_waitcnt lgkmcnt(0)" ::: "memory");
  __builtin_amdgcn_s_barrier();
  asm volatile("" ::: "memory");
  DOMFMA(sR);

  // ---- y1 = relu(acc + b1) -> Y fp16 [64][256B] XOR-swizzled ----
  #pragma unroll
  for (int mf = 0; mf < 2; ++mf)
    #pragma unroll
    for (int nf = 0; nf < 2; ++nf) {
      const int col = wc * 32 + nf * 16 + l15;
      const float bb = b1g[col];
      #pragma unroll
      for (int r = 0; r < 4; ++r) {
        float t = acc[mf][nf][r] + bb; t = t > 0.f ? t : 0.f;
        int row = wr * 32 + mf * 16 + j * 4 + r;
        *(unsigned short*)(Y + row * 256 + ((col * 2) ^ ((row & 7) << 4))) = f2h(t);
      }
    }
  __syncthreads();

  // ---- layer 2: y2 = relu(y1 @ W2^T + b2), K=128 ----
  const int g  = w >> 1, ch = w & 1;
  const int erow = g * 16 + l15;
  const int esw  = (erow & 7) << 4;
  f16x8 a2[4];
  {
    const char* base = Y + erow * 256;
    #pragma unroll
    for (int ks = 0; ks < 4; ++ks)
      a2[ks] = *(const f16x8*)(base + ((ks * 64 + j * 16) ^ esw));
  }
  f32x4 acc2[4] = {};
  const unsigned short* w2b = w2h + (size_t)(ch * 64 + l15) * MD + j * 8;
  #pragma unroll
  for (int ks = 0; ks < 4; ++ks)
    #pragma unroll
    for (int nf = 0; nf < 4; ++nf) {
      f16x8 bf = *(const f16x8*)(w2b + (size_t)(nf * 16) * MD + ks * 32);
      acc2[nf] = __builtin_amdgcn_mfma_f32_16x16x32_f16(a2[ks], bf, acc2[nf], 0, 0, 0);
    }
  __syncthreads();   // all Y reads done before overwrite
  #pragma unroll
  for (int nf = 0; nf < 4; ++nf) {
    const int col = ch * 64 + nf * 16 + l15;
    const float bb = b2g[col];
    #pragma unroll
    for (int r = 0; r < 4; ++r) {
      int row = g * 16 + j * 4 + r;
      float t = acc2[nf][r] + bb; t = t > 0.f ? t : 0.f;
      *(unsigned short*)(Y + row * 256 + ((col * 2) ^ ((row & 7) << 4))) = f2h(t);
    }
  }
  __syncthreads();

  // ---- layer 3: heads (N=32 padded, 20 valid) ----
  f16x8 a3[4];
  {
    const char* base = Y + erow * 256;
    #pragma unroll
    for (int ks = 0; ks < 4; ++ks)
      a3[ks] = *(const f16x8*)(base + ((ks * 64 + j * 16) ^ esw));
  }
  f32x4 acc3 = {};
  const int col3 = ch * 16 + l15;
  const unsigned short* wqb = wqvh + (size_t)col3 * MD + j * 8;
  #pragma unroll
  for (int ks = 0; ks < 4; ++ks) {
    f16x8 bf = *(const f16x8*)(wqb + ks * 32);
    acc3 = __builtin_amdgcn_mfma_f32_16x16x32_f16(a3[ks], bf, acc3, 0, 0, 0);
  }
  if (col3 < 2 * NH) {
    const float badd = (col3 < NH) ? 0.f : bvg[col3 - NH];
    const size_t plane = (size_t)col3 * SB;
    #pragma unroll
    for (int r = 0; r < 4; ++r) {
      int s = m0 + g * 16 + j * 4 + r;
      lv[plane + s] = acc3[r] + badd;
    }
  }
}

// ---------------- sliding-window softmax + per-chunk max ----------------
__global__ void windows_k(const float* __restrict__ lv, const int* __restrict__ mask,
                          float* __restrict__ partial) {
  const int chunk = blockIdx.x, b = blockIdx.y, h = blockIdx.z;
  const int t0 = chunk * 256;
  const int tid = threadIdx.x;
  __shared__ float lsh[272], vsh[272];
  const float* lp = lv + (size_t)h * SB + b * SLEN;
  const float* vp = lv + (size_t)(NH + h) * SB + b * SLEN;
  const int* mp = mask + b * SLEN;
  for (int i = tid; i < 256 + WIN - 1; i += 256) {
    int t = t0 + i;
    if (t < SLEN) {
      float l = lp[t];
      if (mp[t] == 0) l = NEGV;
      lsh[i] = l; vsh[i] = vp[t];
    }
  }
  __syncthreads();
  float wmax = -INFINITY;
  int t = t0 + tid;
  if (t < TLEN) {
    float m = lsh[tid];
    #pragma unroll
    for (int jj = 1; jj < WIN; ++jj) m = fmaxf(m, lsh[tid + jj]);
    float den = 0.f, num = 0.f;
    #pragma unroll
    for (int jj = 0; jj < WIN; ++jj) {
      float e = __expf(lsh[tid + jj] - m);
      den += e; num += e * vsh[tid + jj];
    }
    wmax = num / den;
  }
  #pragma unroll
  for (int o = 32; o > 0; o >>= 1) wmax = fmaxf(wmax, __shfl_down(wmax, o, 64));
  __shared__ float red[4];
  if ((tid & 63) == 0) red[tid >> 6] = wmax;
  __syncthreads();
  if (tid == 0) {
    float r = fmaxf(fmaxf(red[0], red[1]), fmaxf(red[2], red[3]));
    partial[(b * NH + h) * 16 + chunk] = r;
  }
}

// ---------------- final: max over chunks, sum heads, + bias ----------------
__global__ void finalize_k(const float* __restrict__ partial, const float* __restrict__ bias,
                           float* __restrict__ out) {
  const int tid = threadIdx.x;  // 1 block, 128 thr
  __shared__ float hm[80];
  if (tid < NB * NH) {
    float m = -INFINITY;
    #pragma unroll
    for (int c = 0; c < 16; ++c) m = fmaxf(m, partial[tid * 16 + c]);
    hm[tid] = m;
  }
  __syncthreads();
  if (tid < NB) {
    float s = bias[0];
    #pragma unroll
    for (int h = 0; h < NH; ++h) s += hm[tid * NH + h];
    out[tid] = s;
  }
}

extern "C" void kernel_launch(void* const* d_in, const int* in_sizes, int n_in,
                              void* d_out, int out_size, void* d_ws, size_t ws_size,
                              hipStream_t stream) {
  const float* x    = (const float*)d_in[0];
  const int*   mask = (const int*)d_in[1];
  const float* W1   = (const float*)d_in[2];
  const float* b1   = (const float*)d_in[3];
  const float* W2   = (const float*)d_in[4];
  const float* b2   = (const float*)d_in[5];
  const float* Wq   = (const float*)d_in[6];
  const float* Wv   = (const float*)d_in[7];
  const float* bv   = (const float*)d_in[8];
  const float* bias = (const float*)d_in[9];

  char* ws = (char*)d_ws;
  unsigned short* w1h  = (unsigned short*)ws;                   // 1,048,576 B
  unsigned short* w2h  = (unsigned short*)(ws + 1048576);       //    32,768 B
  unsigned short* wqvh = (unsigned short*)(ws + 1081344);       //     8,192 B
  float* lv            = (float*)(ws + 1089536);                // 20*32768*4 = 2,621,440 B
  float* partial       = (float*)(ws + 3710976);                //     5,120 B
  float* out = (float*)d_out;

  hipLaunchKernelGGL(convert_k, dim3(2048), dim3(256), 0, stream, W1, W2, Wq, Wv, w1h, w2h, wqvh);
  hipLaunchKernelGGL(fused_mlp, dim3(SB / 64), dim3(512), LDSZ, stream,
                     x, b1, b2, bv, w1h, w2h, wqvh, lv);
  hipLaunchKernelGGL(windows_k, dim3(16, NB, NH), dim3(256), 0, stream, lv, mask, partial);
  hipLaunchKernelGGL(finalize_k, dim3(1), dim3(128), 0, stream, partial, bias, out);
}